// Round 21
// baseline (647.241 us; speedup 1.0000x reference)
//
#include <hip/hip_runtime.h>
#include <cstdint>
#include <cstddef>

#define B_SZ 8
#define T_LEN 4096
#define HD 1024
#define MTOT (B_SZ * T_LEN)   // 32768 tokens

typedef unsigned short u16;
typedef __attribute__((ext_vector_type(8))) short bf16x8;
typedef __attribute__((ext_vector_type(8))) unsigned short us8;
typedef __attribute__((ext_vector_type(4))) float f32x4;
typedef __attribute__((ext_vector_type(16))) float f32x16;

static __device__ __forceinline__ float bf2f(u16 u) {
    union { unsigned i; float f; } v; v.i = ((unsigned)u) << 16; return v.f;
}
static __device__ __forceinline__ u16 f2bf(float f) {
    union { float f; unsigned i; } v; v.f = f;
    unsigned r = v.i + 0x7fffu + ((v.i >> 16) & 1u);
    return (u16)(r >> 16);
}
static __device__ __forceinline__ float sigm(float x) { return 1.f / (1.f + __expf(-x)); }
static __device__ __forceinline__ float tanh_fast(float x) { return 1.f - 2.f / (1.f + __expf(2.f * x)); }
static __device__ __forceinline__ float f4get(const float4& f, int k) {
    return k == 0 ? f.x : k == 1 ? f.y : k == 2 ? f.z : f.w;   // k static post-unroll
}

static __device__ __forceinline__ void gload_lds16(const void* g, void* l) {
    __builtin_amdgcn_global_load_lds((const __attribute__((address_space(1))) void*)g,
                                     (__attribute__((address_space(3))) void*)l, 16, 0, 0);
}

// ---- K0+K1 fused: weight conversion (blocks 0..5119) + LayerNorm (blocks 5120..)
// wcat = [v(1024); g/t INTERLEAVED (2048: row 1024+2d = Wg[d], 1024+2d+1 = Wt[d]); r(1024)]
__global__ __launch_bounds__(256) void prep_ln(
    const float* __restrict__ Wp, const float* __restrict__ Wg,
    const float* __restrict__ Wt, const float* __restrict__ Wr,
    const float* __restrict__ Wo, u16* __restrict__ wcat, u16* __restrict__ wob,
    const float* __restrict__ x, const float* __restrict__ gamma,
    const float* __restrict__ beta, const float* __restrict__ bp,
    u16* __restrict__ xnb, float* __restrict__ u)
{
    const int tid = threadIdx.x;
    if (blockIdx.x < 5120) {                       // ---- weight prep path ----
        int i = blockIdx.x * 256 + tid;            // float4 index
        const int T1 = 4096 * 256;
        const int T2 = 1024 * 256;
        if (i < T1) {
            int r = i >> 8, kq = i & 255;
            float4 v;
            if      (r < 1024)  v = ((const float4*)Wp)[(size_t)(r + 1) * 256 + kq];
            else if (r < 3072) {
                const int d = (r - 1024) >> 1;
                if (((r - 1024) & 1) == 0) v = ((const float4*)Wg)[(size_t)d * 256 + kq];
                else                       v = ((const float4*)Wt)[(size_t)d * 256 + kq];
            }
            else                v = ((const float4*)Wr)[(size_t)(r - 3072) * 256 + kq];
            ushort4 o; o.x = f2bf(v.x); o.y = f2bf(v.y); o.z = f2bf(v.z); o.w = f2bf(v.w);
            ((ushort4*)wcat)[i] = o;
        } else if (i < T1 + T2) {
            int j = i - T1;
            float4 v = ((const float4*)Wo)[j];
            ushort4 o; o.x = f2bf(v.x); o.y = f2bf(v.y); o.z = f2bf(v.z); o.w = f2bf(v.w);
            ((ushort4*)wob)[j] = o;
        }
        return;
    }
    // ---- LayerNorm path ----
    __shared__ float red[8];
    const int row = blockIdx.x - 5120;
    const float4 v = ((const float4*)(x + (size_t)row * HD))[tid];
    float s  = v.x + v.y + v.z + v.w;
    float sq = v.x * v.x + v.y * v.y + v.z * v.z + v.w * v.w;
    #pragma unroll
    for (int off = 32; off > 0; off >>= 1) {
        s  += __shfl_down(s, off);
        sq += __shfl_down(sq, off);
    }
    if ((tid & 63) == 0) { red[tid >> 6] = s; red[4 + (tid >> 6)] = sq; }
    __syncthreads();
    const float S   = red[0] + red[1] + red[2] + red[3];
    const float SQ  = red[4] + red[5] + red[6] + red[7];
    const float mu  = S * (1.f / HD);
    const float var = SQ * (1.f / HD) - mu * mu;
    const float rs  = rsqrtf(var + 1e-5f);
    const float4 gg = ((const float4*)gamma)[tid];
    const float4 bb = ((const float4*)beta)[tid];
    const float x0 = (v.x - mu) * rs * gg.x + bb.x;
    const float x1 = (v.y - mu) * rs * gg.y + bb.y;
    const float x2 = (v.z - mu) * rs * gg.z + bb.z;
    const float x3 = (v.w - mu) * rs * gg.w + bb.w;
    ushort4 o; o.x = f2bf(x0); o.y = f2bf(x1); o.z = f2bf(x2); o.w = f2bf(x3);
    ((ushort4*)(xnb + (size_t)row * HD))[tid] = o;
    const float4 w0 = ((const float4*)Wp)[tid];
    float su = x0 * w0.x + x1 * w0.y + x2 * w0.z + x3 * w0.w;
    #pragma unroll
    for (int off = 32; off > 0; off >>= 1) su += __shfl_down(su, off);
    __syncthreads();
    if ((tid & 63) == 0) red[tid >> 6] = su;
    __syncthreads();
    if (tid == 0) u[row] = red[0] + red[1] + red[2] + red[3] + bp[0];
}

// ---- K2/K4: bf16 MFMA GEMM, 256x256 tile, 16 waves (4M x 4N, 64x64/wave),
// BK=64, 32x32x16 MFMA, dbuf 128 KiB LDS.
// r21: PER-PHASE BARRIERS (r12's verified mechanism ported to this config).
// Per slab t, 4 phases (one per K=16 step ks):
//   { 4 ds_read (buf p) ; ph0: 2 A-stages / ph1: 2 B-stages of slab t+1 ->
//     buf p^1 ; SB ; s_barrier ; lgkmcnt(0) ; SB ; setprio(1) 4 MFMA setprio(0) ;
//     SB ; [ph3 only: vmcnt(0) ; SB] ; s_barrier }
// Hazards (isomorphic to r12's verified loop): stages target buf p^1 whose
// readers all finished before the PREVIOUS iter's final barrier; slab t+1's
// 4 loads drain at ph3's vmcnt(0) with >=2 phases of flight; rule-#18 fences
// after every inline-asm wait. Intra-iter barriers only stagger waves.
// MODE 0 epilogue (transposed, swapped-operand), NON-TEMPORAL plane stores:
//   ntile 0-3 -> V (bf16,+bias); 4-11 -> P = fp16(sigm(g)*tanh(t)); 12-15 -> R.
// MODE 1: normal orientation, f32 [m][1024] store.
template<int MODE>
__global__ __launch_bounds__(1024, 4) void gemm256(
    const u16* __restrict__ A, const u16* __restrict__ W,
    const float* __restrict__ bp,
    u16* __restrict__ Vt, u16* __restrict__ Pt, u16* __restrict__ Rt,
    float* __restrict__ Cout)
{
    __shared__ u16 sA[2][256 * 64];   // 64 KiB
    __shared__ u16 sB[2][256 * 64];   // 64 KiB
    const int mtile = blockIdx.x, ntile = blockIdx.y;
    const int tid = threadIdx.x;
    const int lane = tid & 63, wave = tid >> 6;
    const int wm = wave >> 2, wn = wave & 3;     // 4M x 4N wave grid, 64x64 per wave
    const u16* Ab = A + (size_t)mtile * 256 * 1024;
    const u16* Wb = W + (size_t)ntile * 256 * 1024;

    // staging: slab = 2048 chunks (16B) per matrix; thread stages 2 chunks of A and B.
    int goff[2], loff[2];
    #pragma unroll
    for (int jj = 0; jj < 2; ++jj) {
        const int q = jj * 1024 + tid;           // chunk id 0..2047
        const int r = q >> 3;                    // row 0..255
        goff[jj] = r * 1024 + ((q & 7) ^ (r & 7)) * 8;
        loff[jj] = q * 8;
    }
    auto stageA = [&](int pb, int kt) {
        #pragma unroll
        for (int jj = 0; jj < 2; ++jj)
            gload_lds16(Ab + goff[jj] + kt * 64, &sA[pb][loff[jj]]);
    };
    auto stageB = [&](int pb, int kt) {
        #pragma unroll
        for (int jj = 0; jj < 2; ++jj)
            gload_lds16(Wb + goff[jj] + kt * 64, &sB[pb][loff[jj]]);
    };

    f32x16 acc[2][2] = {};
    const int rl32  = lane & 31;                 // row-within-32
    const int khalf = lane >> 5;                 // k-half 0/1
    const int sw    = lane & 7;                  // swizzle key
    const int abase = (wm * 64 + rl32) * 64;     // u16 units
    const int bbase = (wn * 64 + rl32) * 64;

    stageA(0, 0); stageB(0, 0);
    asm volatile("s_waitcnt vmcnt(0)" ::: "memory");
    __builtin_amdgcn_sched_barrier(0);
    __builtin_amdgcn_s_barrier();

    for (int t = 0; t < 16; ++t) {
        const int p = t & 1;
        #pragma unroll
        for (int ks = 0; ks < 4; ++ks) {                   // four phases per slab
            const int cs = (ks * 2 + khalf) ^ sw;
            bf16x8 aR[2], bR[2];
            #pragma unroll
            for (int sm = 0; sm < 2; ++sm)
                aR[sm] = *(const bf16x8*)(&sA[p][abase + sm * 2048 + cs * 8]);
            #pragma unroll
            for (int sn = 0; sn < 2; ++sn)
                bR[sn] = *(const bf16x8*)(&sB[p][bbase + sn * 2048 + cs * 8]);
            if (t < 15) {
                if (ks == 0) stageA(p ^ 1, t + 1);         // 2 loads: slab t+1 A
                if (ks == 1) stageB(p ^ 1, t + 1);         // 2 loads: slab t+1 B
            }
            __builtin_amdgcn_sched_barrier(0);
            __builtin_amdgcn_s_barrier();                  // stagger waves into phase ks
            asm volatile("s_waitcnt lgkmcnt(0)" ::: "memory");
            __builtin_amdgcn_sched_barrier(0);             // rule #18: MFMA must not hoist
            __builtin_amdgcn_s_setprio(1);
            #pragma unroll
            for (int sm = 0; sm < 2; ++sm)
                #pragma unroll
                for (int sn = 0; sn < 2; ++sn) {
                    if (MODE == 0)   // swapped operands -> D[d][m] (transposed)
                        acc[sm][sn] = __builtin_amdgcn_mfma_f32_32x32x16_bf16(bR[sn], aR[sm], acc[sm][sn], 0, 0, 0);
                    else
                        acc[sm][sn] = __builtin_amdgcn_mfma_f32_32x32x16_bf16(aR[sm], bR[sn], acc[sm][sn], 0, 0, 0);
                }
            __builtin_amdgcn_s_setprio(0);
            __builtin_amdgcn_sched_barrier(0);
            if (ks == 3) {                                 // gate: slab t+1 landed (all waves)
                asm volatile("s_waitcnt vmcnt(0)" ::: "memory");
                __builtin_amdgcn_sched_barrier(0);
            }
            __builtin_amdgcn_s_barrier();
        }
    }

    if (MODE == 1) {
        #pragma unroll
        for (int sm = 0; sm < 2; ++sm) {
            #pragma unroll
            for (int sn = 0; sn < 2; ++sn) {
                const int n = ntile * 256 + wn * 64 + sn * 32 + rl32;
                #pragma unroll
                for (int r = 0; r < 16; ++r) {
                    const int m = mtile * 256 + wm * 64 + sm * 32 + (r & 3) + 8 * (r >> 2) + 4 * khalf;
                    Cout[(size_t)m * 1024 + n] = acc[sm][sn][r];
                }
            }
        }
    } else if (ntile < 4 || ntile >= 12) {
        const bool isV = (ntile < 4);
        #pragma unroll
        for (int sn = 0; sn < 2; ++sn) {
            #pragma unroll
            for (int r = 0; r < 16; ++r) {
                const int d = (ntile & 3) * 256 + wn * 64 + sn * 32 + (r & 3) + 8 * (r >> 2) + 4 * khalf;
                const size_t drow = (size_t)d * MTOT;
                #pragma unroll
                for (int sm = 0; sm < 2; ++sm) {          // two complete 64B lines per store
                    const int m = mtile * 256 + wm * 64 + sm * 32 + rl32;
                    const float val = acc[sm][sn][r];
                    if (isV) __builtin_nontemporal_store(f2bf(val + bp[1 + d]), &Vt[drow + m]);
                    else     __builtin_nontemporal_store(f2bf(sigm(val)),       &Rt[drow + m]);
                }
            }
        }
    } else {                                     // GT-fused: P = fp16(sigm(g)*tanh(t))
        #pragma unroll
        for (int sn = 0; sn < 2; ++sn) {
            #pragma unroll
            for (int j = 0; j < 8; ++j) {        // acc row pairs (2j, 2j+1)
                const int lrow = (ntile - 4) * 256 + wn * 64 + sn * 32
                               + ((2 * j) & 3) + 8 * (j >> 1) + 4 * khalf;   // even
                const int d = lrow >> 1;
                const size_t drow = (size_t)d * MTOT;
                #pragma unroll
                for (int sm = 0; sm < 2; ++sm) {
                    const int m = mtile * 256 + wm * 64 + sm * 32 + rl32;
                    union { u16 u; _Float16 h; } pc;
                    pc.h = (_Float16)(sigm(acc[sm][sn][2 * j]) * tanh_fast(acc[sm][sn][2 * j + 1]));
                    __builtin_nontemporal_store(pc.u, &Pt[drow + m]);
                }
            }
        }
    }
}

// ---- K3: LDS-free sequential dual cumsum, 3 streams (V, P-fp16, R), depth-3 --
// (r17/r20 config — measured best; depth-6 was null-to-negative in r19.)
__global__ __launch_bounds__(64) void scan_t(
    const u16* __restrict__ Vt, const u16* __restrict__ Pt,
    const u16* __restrict__ Rt,
    const float* __restrict__ ub, u16* __restrict__ outb,
    float* __restrict__ act_last, float* __restrict__ gho_last)
{
    const int lane = threadIdx.x;
    const int b  = blockIdx.x >> 4;
    const int d  = ((blockIdx.x & 15) << 6) + lane;
    const int bm0 = b * T_LEN;
    const size_t rbase = (size_t)d * MTOT + bm0;
    const us8* pv = (const us8*)(Vt + rbase);
    const us8* pp = (const us8*)(Pt + rbase);
    const us8* pr = (const us8*)(Rt + rbase);
    const float4* pu = (const float4*)(ub + bm0);   // block-uniform -> scalarized

    us8 sv[4][2], sp[4][2], sr[4][2];
    float4 su[4][4];

    #pragma unroll
    for (int c = 0; c < 3; ++c) {
        #pragma unroll
        for (int h = 0; h < 2; ++h) {
            sv[c][h] = pv[c * 2 + h]; sp[c][h] = pp[c * 2 + h]; sr[c][h] = pr[c * 2 + h];
        }
        #pragma unroll
        for (int q = 0; q < 4; ++q) su[c][q] = pu[c * 4 + q];
    }

    float acc_a = 0.f;
    _Float16 acc_g = (_Float16)0.f;

    for (int cq = 0; cq < 64; ++cq) {
        #pragma unroll
        for (int s = 0; s < 4; ++s) {                       // slot indices static
            const int c = cq * 4 + s;
            const int cn = c + 3;
            const int sl = (s + 3) & 3;
            if (cn < 256) {
                #pragma unroll
                for (int h = 0; h < 2; ++h) {
                    sv[sl][h] = pv[cn * 2 + h]; sp[sl][h] = pp[cn * 2 + h]; sr[sl][h] = pr[cn * 2 + h];
                }
                #pragma unroll
                for (int q = 0; q < 4; ++q) su[sl][q] = pu[cn * 4 + q];
            }
            #pragma unroll
            for (int e16 = 0; e16 < 16; ++e16) {
                const int h = e16 >> 3, e = e16 & 7;
                const float v  = bf2f(sv[s][h][e]);
                const float r  = bf2f(sr[s][h][e]);
                const float uu = f4get(su[s][e16 >> 2], e16 & 3);
                union { u16 u; _Float16 hh; } pc; pc.u = sp[s][h][e];
                acc_a = fmaf(uu, v, acc_a);                 // f32 sequential cumsum
                acc_g = acc_g + pc.hh;                      // fp16 RNE sequential cumsum
                const float comb = acc_a + (float)acc_g;
                outb[(size_t)(bm0 + c * 16 + e16) * HD + d] = f2bf(r * comb);
            }
        }
    }
    act_last[(size_t)b * HD + d] = acc_a;
    gho_last[(size_t)b * HD + d] = (float)acc_g;
}

extern "C" void kernel_launch(void* const* d_in, const int* in_sizes, int n_in,
                              void* d_out, int out_size, void* d_ws, size_t ws_size,
                              hipStream_t stream)
{
    const float* x   = (const float*)d_in[0];
    const float* gam = (const float*)d_in[1];
    const float* bet = (const float*)d_in[2];
    const float* Wp  = (const float*)d_in[3];
    const float* bp  = (const float*)d_in[4];
    const float* Wg  = (const float*)d_in[5];
    const float* Wt  = (const float*)d_in[6];
    const float* Wr  = (const float*)d_in[7];
    const float* Wo  = (const float*)d_in[8];

    float* out0     = (float*)d_out;                       // (B,T,H) f32
    float* act_last = out0 + (size_t)MTOT * HD;            // (B,D) f32
    float* gho_last = act_last + (size_t)B_SZ * HD;        // (B,D) fp16-valued f32

    char* ws = (char*)d_ws;
    const size_t SZ = (size_t)MTOT * HD * 2;               // 64 MiB per bf16 plane
    u16* xnb  = (u16*)(ws);                                // xn bf16; later scan output
    u16* Vt   = (u16*)(ws + SZ);                           // transposed planes [d][MTOT]
    u16* Pt   = (u16*)(ws + 2 * SZ);                       // fused fp16 g*t plane
    u16* Rt   = (u16*)(ws + 3 * SZ);
    u16* wcat = (u16*)(ws + 4 * SZ);                       // 8,388,608 B
    u16* wob  = (u16*)(ws + 4 * SZ + 8388608);             // 2,097,152 B
    float* ub = (float*)(ws + 4 * SZ + 8388608 + 2097152); // 131,072 B

    prep_ln<<<5120 + MTOT, 256, 0, stream>>>(Wp, Wg, Wt, Wr, Wo, wcat, wob,
                                             x, gam, bet, bp, xnb, ub);
    gemm256<0><<<dim3(128, 16), 1024, 0, stream>>>(xnb, wcat, bp, Vt, Pt, Rt, nullptr);
    scan_t<<<128, 64, 0, stream>>>(Vt, Pt, Rt, ub, xnb /*out*/, act_last, gho_last);
    gemm256<1><<<dim3(128, 4), 1024, 0, stream>>>(xnb, wob, bp, nullptr, nullptr, nullptr, out0);
}

// Round 22
// 572.198 us; speedup vs baseline: 1.1311x; 1.1311x over previous
//
#include <hip/hip_runtime.h>
#include <cstdint>
#include <cstddef>

#define B_SZ 8
#define T_LEN 4096
#define HD 1024
#define MTOT (B_SZ * T_LEN)   // 32768 tokens

typedef unsigned short u16;
typedef __attribute__((ext_vector_type(8))) short bf16x8;
typedef __attribute__((ext_vector_type(8))) unsigned short us8;
typedef __attribute__((ext_vector_type(4))) float f32x4;
typedef __attribute__((ext_vector_type(16))) float f32x16;

static __device__ __forceinline__ float bf2f(u16 u) {
    union { unsigned i; float f; } v; v.i = ((unsigned)u) << 16; return v.f;
}
static __device__ __forceinline__ u16 f2bf(float f) {
    union { float f; unsigned i; } v; v.f = f;
    unsigned r = v.i + 0x7fffu + ((v.i >> 16) & 1u);
    return (u16)(r >> 16);
}
static __device__ __forceinline__ float sigm(float x) { return 1.f / (1.f + __expf(-x)); }
static __device__ __forceinline__ float tanh_fast(float x) { return 1.f - 2.f / (1.f + __expf(2.f * x)); }
static __device__ __forceinline__ float f4get(const float4& f, int k) {
    return k == 0 ? f.x : k == 1 ? f.y : k == 2 ? f.z : f.w;   // k static post-unroll
}

static __device__ __forceinline__ void gload_lds16(const void* g, void* l) {
    __builtin_amdgcn_global_load_lds((const __attribute__((address_space(1))) void*)g,
                                     (__attribute__((address_space(3))) void*)l, 16, 0, 0);
}

// ---- K0+K1 fused: weight conversion (blocks 0..5119) + LayerNorm (blocks 5120..)
// wcat = [v(1024); g/t INTERLEAVED (2048: row 1024+2d = Wg[d], 1024+2d+1 = Wt[d]); r(1024)]
__global__ __launch_bounds__(256) void prep_ln(
    const float* __restrict__ Wp, const float* __restrict__ Wg,
    const float* __restrict__ Wt, const float* __restrict__ Wr,
    const float* __restrict__ Wo, u16* __restrict__ wcat, u16* __restrict__ wob,
    const float* __restrict__ x, const float* __restrict__ gamma,
    const float* __restrict__ beta, const float* __restrict__ bp,
    u16* __restrict__ xnb, float* __restrict__ u)
{
    const int tid = threadIdx.x;
    if (blockIdx.x < 5120) {                       // ---- weight prep path ----
        int i = blockIdx.x * 256 + tid;            // float4 index
        const int T1 = 4096 * 256;
        const int T2 = 1024 * 256;
        if (i < T1) {
            int r = i >> 8, kq = i & 255;
            float4 v;
            if      (r < 1024)  v = ((const float4*)Wp)[(size_t)(r + 1) * 256 + kq];
            else if (r < 3072) {
                const int d = (r - 1024) >> 1;
                if (((r - 1024) & 1) == 0) v = ((const float4*)Wg)[(size_t)d * 256 + kq];
                else                       v = ((const float4*)Wt)[(size_t)d * 256 + kq];
            }
            else                v = ((const float4*)Wr)[(size_t)(r - 3072) * 256 + kq];
            ushort4 o; o.x = f2bf(v.x); o.y = f2bf(v.y); o.z = f2bf(v.z); o.w = f2bf(v.w);
            ((ushort4*)wcat)[i] = o;
        } else if (i < T1 + T2) {
            int j = i - T1;
            float4 v = ((const float4*)Wo)[j];
            ushort4 o; o.x = f2bf(v.x); o.y = f2bf(v.y); o.z = f2bf(v.z); o.w = f2bf(v.w);
            ((ushort4*)wob)[j] = o;
        }
        return;
    }
    // ---- LayerNorm path ----
    __shared__ float red[8];
    const int row = blockIdx.x - 5120;
    const float4 v = ((const float4*)(x + (size_t)row * HD))[tid];
    float s  = v.x + v.y + v.z + v.w;
    float sq = v.x * v.x + v.y * v.y + v.z * v.z + v.w * v.w;
    #pragma unroll
    for (int off = 32; off > 0; off >>= 1) {
        s  += __shfl_down(s, off);
        sq += __shfl_down(sq, off);
    }
    if ((tid & 63) == 0) { red[tid >> 6] = s; red[4 + (tid >> 6)] = sq; }
    __syncthreads();
    const float S   = red[0] + red[1] + red[2] + red[3];
    const float SQ  = red[4] + red[5] + red[6] + red[7];
    const float mu  = S * (1.f / HD);
    const float var = SQ * (1.f / HD) - mu * mu;
    const float rs  = rsqrtf(var + 1e-5f);
    const float4 gg = ((const float4*)gamma)[tid];
    const float4 bb = ((const float4*)beta)[tid];
    const float x0 = (v.x - mu) * rs * gg.x + bb.x;
    const float x1 = (v.y - mu) * rs * gg.y + bb.y;
    const float x2 = (v.z - mu) * rs * gg.z + bb.z;
    const float x3 = (v.w - mu) * rs * gg.w + bb.w;
    ushort4 o; o.x = f2bf(x0); o.y = f2bf(x1); o.z = f2bf(x2); o.w = f2bf(x3);
    ((ushort4*)(xnb + (size_t)row * HD))[tid] = o;
    const float4 w0 = ((const float4*)Wp)[tid];
    float su = x0 * w0.x + x1 * w0.y + x2 * w0.z + x3 * w0.w;
    #pragma unroll
    for (int off = 32; off > 0; off >>= 1) su += __shfl_down(su, off);
    __syncthreads();
    if ((tid & 63) == 0) red[tid >> 6] = su;
    __syncthreads();
    if (tid == 0) u[row] = red[0] + red[1] + red[2] + red[3] + bp[0];
}

// ---- K2/K4: bf16 MFMA GEMM, 256x256 tile, 16 waves (4M x 4N, 64x64/wave),
// BK=64, 32x32x16 MFMA, dbuf 128 KiB LDS, r15-verified single-barrier K-loop.
// (r20 config — the session's best measured: K2 333 us, MfmaUtil 38, total 573.)
// MODE 0 epilogue (transposed, swapped-operand), NON-TEMPORAL plane stores
// (keeps the 64MB A matrix L3-resident; plane data isn't re-read until scan):
//   ntile 0-3 -> V (bf16,+bias); 4-11 -> P = fp16(sigm(g)*tanh(t)) (g/t
//   adjacent acc rows via wcat interleave); 12-15 -> R (bf16, sigmoid).
// MODE 1: normal orientation, f32 [m][1024] store.
template<int MODE>
__global__ __launch_bounds__(1024, 4) void gemm256(
    const u16* __restrict__ A, const u16* __restrict__ W,
    const float* __restrict__ bp,
    u16* __restrict__ Vt, u16* __restrict__ Pt, u16* __restrict__ Rt,
    float* __restrict__ Cout)
{
    __shared__ u16 sA[2][256 * 64];   // 64 KiB
    __shared__ u16 sB[2][256 * 64];   // 64 KiB
    const int mtile = blockIdx.x, ntile = blockIdx.y;
    const int tid = threadIdx.x;
    const int lane = tid & 63, wave = tid >> 6;
    const int wm = wave >> 2, wn = wave & 3;     // 4M x 4N wave grid, 64x64 per wave
    const u16* Ab = A + (size_t)mtile * 256 * 1024;
    const u16* Wb = W + (size_t)ntile * 256 * 1024;

    // staging: slab = 2048 chunks (16B) per matrix; thread stages 2 chunks of A and B.
    int goff[2], loff[2];
    #pragma unroll
    for (int jj = 0; jj < 2; ++jj) {
        const int q = jj * 1024 + tid;           // chunk id 0..2047
        const int r = q >> 3;                    // row 0..255
        goff[jj] = r * 1024 + ((q & 7) ^ (r & 7)) * 8;
        loff[jj] = q * 8;
    }
    auto stage = [&](int pb, int kt) {
        #pragma unroll
        for (int jj = 0; jj < 2; ++jj) {
            gload_lds16(Ab + goff[jj] + kt * 64, &sA[pb][loff[jj]]);
            gload_lds16(Wb + goff[jj] + kt * 64, &sB[pb][loff[jj]]);
        }
    };

    f32x16 acc[2][2] = {};
    const int rl32  = lane & 31;                 // row-within-32
    const int khalf = lane >> 5;                 // k-half 0/1
    const int sw    = lane & 7;                  // swizzle key
    const int abase = (wm * 64 + rl32) * 64;     // u16 units
    const int bbase = (wn * 64 + rl32) * 64;

    stage(0, 0);
    for (int t = 0; t < 16; ++t) {
        const int p = t & 1;
        asm volatile("s_waitcnt vmcnt(0)" ::: "memory");   // slab t (issued last iter) landed
        __builtin_amdgcn_s_barrier();                      // all waves' slab-t writes visible
        __builtin_amdgcn_sched_barrier(0);                 // nothing below crosses above barrier
        if (t < 15) stage(p ^ 1, t + 1);                   // overwrites slab t-1's buf: readers done pre-barrier
        #pragma unroll
        for (int ks = 0; ks < 4; ++ks) {                   // four K=16 steps per slab
            const int cs = (ks * 2 + khalf) ^ sw;
            bf16x8 aR[2], bR[2];
            #pragma unroll
            for (int sm = 0; sm < 2; ++sm)
                aR[sm] = *(const bf16x8*)(&sA[p][abase + sm * 2048 + cs * 8]);
            #pragma unroll
            for (int sn = 0; sn < 2; ++sn)
                bR[sn] = *(const bf16x8*)(&sB[p][bbase + sn * 2048 + cs * 8]);
            __builtin_amdgcn_s_setprio(1);
            #pragma unroll
            for (int sm = 0; sm < 2; ++sm)
                #pragma unroll
                for (int sn = 0; sn < 2; ++sn) {
                    if (MODE == 0)   // swapped operands -> D[d][m] (transposed)
                        acc[sm][sn] = __builtin_amdgcn_mfma_f32_32x32x16_bf16(bR[sn], aR[sm], acc[sm][sn], 0, 0, 0);
                    else
                        acc[sm][sn] = __builtin_amdgcn_mfma_f32_32x32x16_bf16(aR[sm], bR[sn], acc[sm][sn], 0, 0, 0);
                }
            __builtin_amdgcn_s_setprio(0);
        }
    }

    if (MODE == 1) {
        #pragma unroll
        for (int sm = 0; sm < 2; ++sm) {
            #pragma unroll
            for (int sn = 0; sn < 2; ++sn) {
                const int n = ntile * 256 + wn * 64 + sn * 32 + rl32;
                #pragma unroll
                for (int r = 0; r < 16; ++r) {
                    const int m = mtile * 256 + wm * 64 + sm * 32 + (r & 3) + 8 * (r >> 2) + 4 * khalf;
                    Cout[(size_t)m * 1024 + n] = acc[sm][sn][r];
                }
            }
        }
    } else if (ntile < 4 || ntile >= 12) {
        const bool isV = (ntile < 4);
        #pragma unroll
        for (int sn = 0; sn < 2; ++sn) {
            #pragma unroll
            for (int r = 0; r < 16; ++r) {
                const int d = (ntile & 3) * 256 + wn * 64 + sn * 32 + (r & 3) + 8 * (r >> 2) + 4 * khalf;
                const size_t drow = (size_t)d * MTOT;
                #pragma unroll
                for (int sm = 0; sm < 2; ++sm) {          // two complete 64B lines per store
                    const int m = mtile * 256 + wm * 64 + sm * 32 + rl32;
                    const float val = acc[sm][sn][r];
                    if (isV) __builtin_nontemporal_store(f2bf(val + bp[1 + d]), &Vt[drow + m]);
                    else     __builtin_nontemporal_store(f2bf(sigm(val)),       &Rt[drow + m]);
                }
            }
        }
    } else {                                     // GT-fused: P = fp16(sigm(g)*tanh(t))
        #pragma unroll
        for (int sn = 0; sn < 2; ++sn) {
            #pragma unroll
            for (int j = 0; j < 8; ++j) {        // acc row pairs (2j, 2j+1)
                const int lrow = (ntile - 4) * 256 + wn * 64 + sn * 32
                               + ((2 * j) & 3) + 8 * (j >> 1) + 4 * khalf;   // even
                const int d = lrow >> 1;
                const size_t drow = (size_t)d * MTOT;
                #pragma unroll
                for (int sm = 0; sm < 2; ++sm) {
                    const int m = mtile * 256 + wm * 64 + sm * 32 + rl32;
                    union { u16 u; _Float16 h; } pc;
                    pc.h = (_Float16)(sigm(acc[sm][sn][2 * j]) * tanh_fast(acc[sm][sn][2 * j + 1]));
                    __builtin_nontemporal_store(pc.u, &Pt[drow + m]);
                }
            }
        }
    }
}

// ---- K3: LDS-free sequential dual cumsum, 3 streams (V, P-fp16, R), depth-3 --
// (r17/r20 config — measured best; depth-6 was null-to-negative in r19.)
__global__ __launch_bounds__(64) void scan_t(
    const u16* __restrict__ Vt, const u16* __restrict__ Pt,
    const u16* __restrict__ Rt,
    const float* __restrict__ ub, u16* __restrict__ outb,
    float* __restrict__ act_last, float* __restrict__ gho_last)
{
    const int lane = threadIdx.x;
    const int b  = blockIdx.x >> 4;
    const int d  = ((blockIdx.x & 15) << 6) + lane;
    const int bm0 = b * T_LEN;
    const size_t rbase = (size_t)d * MTOT + bm0;
    const us8* pv = (const us8*)(Vt + rbase);
    const us8* pp = (const us8*)(Pt + rbase);
    const us8* pr = (const us8*)(Rt + rbase);
    const float4* pu = (const float4*)(ub + bm0);   // block-uniform -> scalarized

    us8 sv[4][2], sp[4][2], sr[4][2];
    float4 su[4][4];

    #pragma unroll
    for (int c = 0; c < 3; ++c) {
        #pragma unroll
        for (int h = 0; h < 2; ++h) {
            sv[c][h] = pv[c * 2 + h]; sp[c][h] = pp[c * 2 + h]; sr[c][h] = pr[c * 2 + h];
        }
        #pragma unroll
        for (int q = 0; q < 4; ++q) su[c][q] = pu[c * 4 + q];
    }

    float acc_a = 0.f;
    _Float16 acc_g = (_Float16)0.f;

    for (int cq = 0; cq < 64; ++cq) {
        #pragma unroll
        for (int s = 0; s < 4; ++s) {                       // slot indices static
            const int c = cq * 4 + s;
            const int cn = c + 3;
            const int sl = (s + 3) & 3;
            if (cn < 256) {
                #pragma unroll
                for (int h = 0; h < 2; ++h) {
                    sv[sl][h] = pv[cn * 2 + h]; sp[sl][h] = pp[cn * 2 + h]; sr[sl][h] = pr[cn * 2 + h];
                }
                #pragma unroll
                for (int q = 0; q < 4; ++q) su[sl][q] = pu[cn * 4 + q];
            }
            #pragma unroll
            for (int e16 = 0; e16 < 16; ++e16) {
                const int h = e16 >> 3, e = e16 & 7;
                const float v  = bf2f(sv[s][h][e]);
                const float r  = bf2f(sr[s][h][e]);
                const float uu = f4get(su[s][e16 >> 2], e16 & 3);
                union { u16 u; _Float16 hh; } pc; pc.u = sp[s][h][e];
                acc_a = fmaf(uu, v, acc_a);                 // f32 sequential cumsum
                acc_g = acc_g + pc.hh;                      // fp16 RNE sequential cumsum
                const float comb = acc_a + (float)acc_g;
                outb[(size_t)(bm0 + c * 16 + e16) * HD + d] = f2bf(r * comb);
            }
        }
    }
    act_last[(size_t)b * HD + d] = acc_a;
    gho_last[(size_t)b * HD + d] = (float)acc_g;
}

extern "C" void kernel_launch(void* const* d_in, const int* in_sizes, int n_in,
                              void* d_out, int out_size, void* d_ws, size_t ws_size,
                              hipStream_t stream)
{
    const float* x   = (const float*)d_in[0];
    const float* gam = (const float*)d_in[1];
    const float* bet = (const float*)d_in[2];
    const float* Wp  = (const float*)d_in[3];
    const float* bp  = (const float*)d_in[4];
    const float* Wg  = (const float*)d_in[5];
    const float* Wt  = (const float*)d_in[6];
    const float* Wr  = (const float*)d_in[7];
    const float* Wo  = (const float*)d_in[8];

    float* out0     = (float*)d_out;                       // (B,T,H) f32
    float* act_last = out0 + (size_t)MTOT * HD;            // (B,D) f32
    float* gho_last = act_last + (size_t)B_SZ * HD;        // (B,D) fp16-valued f32

    char* ws = (char*)d_ws;
    const size_t SZ = (size_t)MTOT * HD * 2;               // 64 MiB per bf16 plane
    u16* xnb  = (u16*)(ws);                                // xn bf16; later scan output
    u16* Vt   = (u16*)(ws + SZ);                           // transposed planes [d][MTOT]
    u16* Pt   = (u16*)(ws + 2 * SZ);                       // fused fp16 g*t plane
    u16* Rt   = (u16*)(ws + 3 * SZ);
    u16* wcat = (u16*)(ws + 4 * SZ);                       // 8,388,608 B
    u16* wob  = (u16*)(ws + 4 * SZ + 8388608);             // 2,097,152 B
    float* ub = (float*)(ws + 4 * SZ + 8388608 + 2097152); // 131,072 B

    prep_ln<<<5120 + MTOT, 256, 0, stream>>>(Wp, Wg, Wt, Wr, Wo, wcat, wob,
                                             x, gam, bet, bp, xnb, ub);
    gemm256<0><<<dim3(128, 16), 1024, 0, stream>>>(xnb, wcat, bp, Vt, Pt, Rt, nullptr);
    scan_t<<<128, 64, 0, stream>>>(Vt, Pt, Rt, ub, xnb /*out*/, act_last, gho_last);
    gemm256<1><<<dim3(128, 4), 1024, 0, stream>>>(xnb, wob, bp, nullptr, nullptr, nullptr, out0);
}